// Round 12
// baseline (234.266 us; speedup 1.0000x reference)
//
#include <hip/hip_runtime.h>
#include <hip/hip_bf16.h>

// CAM: out = (q @ k^T) @ v + v  ==  q @ (k^T @ v) + v.   S[b] = k^T v is 49x49.
// SINGLE fused kernel (R12): the 3-kernel pipeline had a ~30us structural
// floor (launch+ramp+drain x3); all qs-variants R7-R11 plateaued at ~51us.
//   phase 1: ktv streaming MFMA (R8-proven), S accumulated via unsafeAtomicAdd
//            into memset-zeroed fp32 S^T[b][n][m] (device-scope = XCD-coherent).
//   barrier: hand-rolled grid barrier; co-residency by capacity arithmetic:
//            grid 1024 = 4 blocks/CU x 256 CU, launch_bounds(256,4),
//            LDS 23.6KB (cap 6/CU), VGPR <= 128.
//   phase 2: qs MFMA; q staged as NATURAL-layout bf16 rows (A-frag = one
//            aligned ds_read_b128; no transpose needed), S via AGENT-scope
//            atomic loads (bypass stale XCD-local L2), coalesced epilogue.

#define BATCH 128
#define CH    1024
#define NN    49
#define GRID  1024
#define LDQT  56     // bf16 row stride of Qt: 112 B (16-mult; only m<=48 read)
#define LDST  72     // bf16 row stride of Sl : 144 B (16-mult)

typedef short  bf16x8 __attribute__((ext_vector_type(8)));
typedef float  f32x16 __attribute__((ext_vector_type(16)));

__device__ __forceinline__ short f2bf(float x) {
  return __builtin_bit_cast(short, __float2bfloat16(x));   // RNE
}

__global__ __launch_bounds__(256, 4) void cam_kernel(
    const float* __restrict__ Kg, const float* __restrict__ Vg,
    const float* __restrict__ Qg, float* __restrict__ Sf,
    unsigned* __restrict__ ctr, float* __restrict__ Og)
{
  const int tid  = threadIdx.x;
  const int wv   = tid >> 6;
  const int lane = tid & 63;
  const int g    = lane >> 5;
  const int ln   = lane & 31;
  const int i0   = (wv >> 1) * 32;
  const int j0   = (wv & 1)  * 32;
  const int b    = blockIdx.x >> 3;      // same batch mapping both phases
  const int s    = blockIdx.x & 7;

  __shared__ __align__(16) unsigned short Qt[128 * LDQT];  // 14.3 KB
  __shared__ __align__(16) unsigned short Sl[64 * LDST];   //  9.2 KB

  // ================= phase 1: S^T[b] += (K-chunk^T @ V-chunk)^T =============
  {
    const int rowA = min(i0 + ln, NN - 1);   // clamp: dup loads, rows discarded
    const int rowB = min(j0 + ln, NN - 1);
    const size_t cbase = ((size_t)b * CH + (size_t)s * 128) * NN;
    const float* Ka = Kg + cbase + (size_t)(g * 8) * NN + rowA;
    const float* Vb = Vg + cbase + (size_t)(g * 8) * NN + rowB;

    f32x16 acc;
    #pragma unroll
    for (int r = 0; r < 16; ++r) acc[r] = 0.f;

    #pragma unroll 2
    for (int kc = 0; kc < 8; ++kc) {       // 8 chunks x 16 channels
      const float* ka = Ka + (size_t)kc * 16 * NN;
      const float* vb = Vb + (size_t)kc * 16 * NN;
      float kx[8], vx[8];
      #pragma unroll
      for (int e = 0; e < 8; ++e) { kx[e] = ka[e * NN]; vx[e] = vb[e * NN]; }
      bf16x8 ah, bh;
      #pragma unroll
      for (int e = 0; e < 8; ++e) { ah[e] = f2bf(kx[e]); bh[e] = f2bf(vx[e]); }
      acc = __builtin_amdgcn_mfma_f32_32x32x16_bf16(ah, bh, acc, 0, 0, 0);
    }

    // C/D: col(=j) = lane&31, row(=i) = (r&3)+8*(r>>2)+4*g   [m74/m101]
    const int j = j0 + ln;
    if (j < NN) {
      float* sb = Sf + (size_t)b * 4096 + (size_t)j * 64;   // S^T[j][i]
      #pragma unroll
      for (int r = 0; r < 16; ++r) {
        const int i = i0 + (r & 3) + 8 * (r >> 2) + 4 * g;
        if (i < NN) unsafeAtomicAdd(&sb[i], acc[r]);        // HW f32 atomic
      }
    }
  }

  // ================= grid barrier (all 1024 blocks co-resident) =============
  __syncthreads();                         // drains vmcnt -> atomics issued
  if (tid == 0) {
    __threadfence();                       // device-scope release
    atomicAdd(ctr, 1u);
    while (__hip_atomic_load(ctr, __ATOMIC_ACQUIRE, __HIP_MEMORY_SCOPE_AGENT)
           < (unsigned)GRID)
      __builtin_amdgcn_s_sleep(2);
  }
  __syncthreads();

  // ================= phase 2: out[128-row tile] = q @ S + v =================
  {
    const int pr = s;                                  // 8 row-tiles per batch
    const size_t qbase = ((size_t)b * CH + (size_t)pr * 128) * NN;

    // stage 128 q-rows natural-layout bf16 (coalesced reads, linear writes)
    for (int f = tid; f < 128 * NN; f += 256) {
      const int r = f / NN, m = f - r * NN;
      Qt[r * LDQT + m] = (unsigned short)f2bf(Qg[qbase + f]);
    }
    // stage S^T -> bf16 LDS (AGENT loads: coherent vs phase-1 atomics)
    {
      const float* sfb = Sf + (size_t)b * 4096;
      for (int e = tid; e < 4096; e += 256) {
        const int n = e >> 6, m = e & 63;
        float v = 0.f;
        if (m < NN && n < NN)
          v = __hip_atomic_load(&sfb[e], __ATOMIC_RELAXED, __HIP_MEMORY_SCOPE_AGENT);
        Sl[n * LDST + m] = (unsigned short)f2bf(v);    // zero-padded
      }
    }
    __syncthreads();

    const unsigned short* qt0 = &Qt[(i0 + ln) * LDQT];        // tile 0 row
    const unsigned short* qt1 = &Qt[(64 + i0 + ln) * LDQT];   // tile 1 row
    const unsigned short* slb = &Sl[(j0 + ln) * LDST];        // S^T col j

    f32x16 acc0, acc1;
    #pragma unroll
    for (int r = 0; r < 16; ++r) { acc0[r] = 0.f; acc1[r] = 0.f; }

    #pragma unroll
    for (int kc = 0; kc < 3; ++kc) {       // m0 <= 47: all fragment m's valid
      const int m0 = kc * 16 + g * 8;
      const bf16x8 a0 = *(const bf16x8*)&qt0[m0];    // one ds_read_b128
      const bf16x8 a1 = *(const bf16x8*)&qt1[m0];
      const bf16x8 bh = *(const bf16x8*)&slb[m0];
      acc0 = __builtin_amdgcn_mfma_f32_32x32x16_bf16(a0, bh, acc0, 0, 0, 0);
      acc1 = __builtin_amdgcn_mfma_f32_32x32x16_bf16(a1, bh, acc1, 0, 0, 0);
    }
    {                                      // tail: only m=48 real (R8-proven)
      const int m0 = 48 + g * 8;
      bf16x8 a0, a1;
      #pragma unroll
      for (int e = 0; e < 8; ++e) { a0[e] = 0; a1[e] = 0; }
      a0[0] = (g == 0) ? (short)qt0[48] : (short)0;
      a1[0] = (g == 0) ? (short)qt1[48] : (short)0;
      const bf16x8 bh = *(const bf16x8*)&slb[m0];    // zeros at m>=49
      acc0 = __builtin_amdgcn_mfma_f32_32x32x16_bf16(a0, bh, acc0, 0, 0, 0);
      acc1 = __builtin_amdgcn_mfma_f32_32x32x16_bf16(a1, bh, acc1, 0, 0, 0);
    }

    // epilogue: all 64 rows/tile valid; guard col j < 49; coalesced per r
    const int j = j0 + ln;
    if (j < NN) {
      #pragma unroll
      for (int r = 0; r < 16; ++r) {
        const int i = i0 + (r & 3) + 8 * (r >> 2) + 4 * g;
        const size_t o0 = qbase + (size_t)i * NN + j;
        const size_t o1 = qbase + (size_t)(64 + i) * NN + j;
        Og[o0] = acc0[r] + Vg[o0];
        Og[o1] = acc1[r] + Vg[o1];
      }
    }
  }
}

extern "C" void kernel_launch(void* const* d_in, const int* in_sizes, int n_in,
                              void* d_out, int out_size, void* d_ws, size_t ws_size,
                              hipStream_t stream) {
  (void)in_sizes; (void)n_in; (void)out_size; (void)ws_size;
  const float* v1 = (const float*)d_in[0];
  const float* q1 = (const float*)d_in[1];
  const float* k1 = (const float*)d_in[2];
  float* out = (float*)d_out;

  float*    sf  = (float*)d_ws;                       // 128*4096*4 = 2.10 MB
  unsigned* ctr = (unsigned*)((char*)d_ws + (size_t)BATCH * 4096 * 4);

  // zero S accumulator + barrier counter (captured; reruns every replay)
  hipMemsetAsync(d_ws, 0, (size_t)BATCH * 4096 * 4 + 16, stream);
  cam_kernel<<<dim3(GRID), dim3(256), 0, stream>>>(k1, v1, q1, sf, ctr, out);
}

// Round 13
// 188.487 us; speedup vs baseline: 1.2429x; 1.2429x over previous
//
#include <hip/hip_runtime.h>
#include <hip/hip_bf16.h>

// CAM: out = (q @ k^T) @ v + v  ==  q @ (k^T @ v) + v.   S[b] = k^T v is 49x49.
// SINGLE fused kernel v2. R12 proved the grid barrier + co-residency works but
// died on atomic RMW contention (2.4M unsafeAtomicAdd) + scalar coherent loads.
// v2: contention-free cross-phase plumbing.
//   phase 1: ktv streaming MFMA (R8-proven). Partial S per (b,s) stored to a
//            PRIVATE ws slot via agent-scope relaxed stores (write-through, no
//            RMW, no sharing).
//   barrier: hand-rolled grid barrier (R12-proven). 1024 blocks = 4/CU x 256CU,
//            launch_bounds(256,4), LDS 23.5KB (cap 6/CU), VGPR ~40.
//   phase 2: R12-proven qs core. S = reduce of 8 partials via COALESCED
//            agent-scope loads (n-fastest => consecutive addrs) -> bf16 Sl LDS.
// Only the 4-byte counter is memset per replay.

#define BATCH 128
#define CH    1024
#define NN    49
#define GRID  1024
#define LDQT  56     // bf16 row stride of Qt: 112 B (16-mult)
#define LDST  72     // bf16 row stride of Sl : 144 B (16-mult)

typedef short  bf16x8 __attribute__((ext_vector_type(8)));
typedef float  f32x16 __attribute__((ext_vector_type(16)));

__device__ __forceinline__ short f2bf(float x) {
  return __builtin_bit_cast(short, __float2bfloat16(x));   // RNE
}

__global__ __launch_bounds__(256, 4) void cam_kernel(
    const float* __restrict__ Kg, const float* __restrict__ Vg,
    const float* __restrict__ Qg, float* __restrict__ Spart,
    unsigned* __restrict__ ctr, float* __restrict__ Og)
{
  const int tid  = threadIdx.x;
  const int wv   = tid >> 6;
  const int lane = tid & 63;
  const int g    = lane >> 5;
  const int ln   = lane & 31;
  const int i0   = (wv >> 1) * 32;
  const int j0   = (wv & 1)  * 32;
  const int b    = blockIdx.x >> 3;      // same batch mapping both phases
  const int s    = blockIdx.x & 7;

  __shared__ __align__(16) unsigned short Qt[128 * LDQT];  // 14.3 KB
  __shared__ __align__(16) unsigned short Sl[64 * LDST];   //  9.2 KB

  // ================= phase 1: Spart[b,s] = K-chunk^T @ V-chunk ==============
  {
    const int rowA = min(i0 + ln, NN - 1);   // clamp: dup loads, rows discarded
    const int rowB = min(j0 + ln, NN - 1);
    const size_t cbase = ((size_t)b * CH + (size_t)s * 128) * NN;
    const float* Ka = Kg + cbase + (size_t)(g * 8) * NN + rowA;
    const float* Vb = Vg + cbase + (size_t)(g * 8) * NN + rowB;

    f32x16 acc;
    #pragma unroll
    for (int r = 0; r < 16; ++r) acc[r] = 0.f;

    #pragma unroll 2
    for (int kc = 0; kc < 8; ++kc) {       // 8 chunks x 16 channels
      const float* ka = Ka + (size_t)kc * 16 * NN;
      const float* vb = Vb + (size_t)kc * 16 * NN;
      float kx[8], vx[8];
      #pragma unroll
      for (int e = 0; e < 8; ++e) { kx[e] = ka[e * NN]; vx[e] = vb[e * NN]; }
      bf16x8 ah, bh;
      #pragma unroll
      for (int e = 0; e < 8; ++e) { ah[e] = f2bf(kx[e]); bh[e] = f2bf(vx[e]); }
      acc = __builtin_amdgcn_mfma_f32_32x32x16_bf16(ah, bh, acc, 0, 0, 0);
    }

    // C/D: col(=j) = lane&31, row(=i) = (r&3)+8*(r>>2)+4*g   [m74/m101]
    const int j = j0 + ln;
    float* Sp = Spart + (size_t)blockIdx.x * (NN * NN);   // PRIVATE slot
    if (j < NN) {
      #pragma unroll
      for (int r = 0; r < 16; ++r) {
        const int i = i0 + (r & 3) + 8 * (r >> 2) + 4 * g;
        if (i < NN)
          __hip_atomic_store(&Sp[i * NN + j], acc[r],
                             __ATOMIC_RELAXED, __HIP_MEMORY_SCOPE_AGENT);
      }
    }
  }

  // ================= grid barrier (R12-proven) ==============================
  __syncthreads();                         // compiler drains vmcnt before bar
  if (tid == 0) {
    __threadfence();                       // device-scope release
    atomicAdd(ctr, 1u);
    while (__hip_atomic_load(ctr, __ATOMIC_ACQUIRE, __HIP_MEMORY_SCOPE_AGENT)
           < (unsigned)GRID)
      __builtin_amdgcn_s_sleep(2);
  }
  __syncthreads();

  // ================= phase 2: out[128-row tile] = q @ S + v =================
  {
    const int pr = s;                                  // 8 row-tiles per batch
    const size_t qbase = ((size_t)b * CH + (size_t)pr * 128) * NN;

    // stage 128 q-rows natural-layout bf16 (coalesced reads, linear writes)
    for (int f = tid; f < 128 * NN; f += 256) {
      const int r = f / NN, m = f - r * NN;
      Qt[r * LDQT + m] = (unsigned short)f2bf(Qg[qbase + f]);
    }
    // reduce 8 partials -> Sl[n][m] bf16 (coalesced agent loads: n fastest)
    {
      const float* sb = Spart + (size_t)(b * 8) * (NN * NN);
      for (int e = tid; e < 4096; e += 256) {
        const int m = e >> 6, n = e & 63;
        float v = 0.f;
        if (m < NN && n < NN) {
          const int off = m * NN + n;
          #pragma unroll
          for (int sp = 0; sp < 8; ++sp)
            v += __hip_atomic_load(&sb[(size_t)sp * (NN * NN) + off],
                                   __ATOMIC_RELAXED, __HIP_MEMORY_SCOPE_AGENT);
        }
        Sl[n * LDST + m] = (unsigned short)f2bf(v);    // zero-padded
      }
    }
    __syncthreads();

    const unsigned short* qt0 = &Qt[(i0 + ln) * LDQT];        // tile 0 row
    const unsigned short* qt1 = &Qt[(64 + i0 + ln) * LDQT];   // tile 1 row
    const unsigned short* slb = &Sl[(j0 + ln) * LDST];        // S^T row j

    f32x16 acc0, acc1;
    #pragma unroll
    for (int r = 0; r < 16; ++r) { acc0[r] = 0.f; acc1[r] = 0.f; }

    #pragma unroll
    for (int kc = 0; kc < 3; ++kc) {       // m0 <= 47: all fragment m's valid
      const int m0 = kc * 16 + g * 8;
      const bf16x8 a0 = *(const bf16x8*)&qt0[m0];    // one ds_read_b128
      const bf16x8 a1 = *(const bf16x8*)&qt1[m0];
      const bf16x8 bh = *(const bf16x8*)&slb[m0];
      acc0 = __builtin_amdgcn_mfma_f32_32x32x16_bf16(a0, bh, acc0, 0, 0, 0);
      acc1 = __builtin_amdgcn_mfma_f32_32x32x16_bf16(a1, bh, acc1, 0, 0, 0);
    }
    {                                      // tail: only m=48 real (R12-proven)
      const int m0 = 48 + g * 8;
      bf16x8 a0, a1;
      #pragma unroll
      for (int e = 0; e < 8; ++e) { a0[e] = 0; a1[e] = 0; }
      a0[0] = (g == 0) ? (short)qt0[48] : (short)0;
      a1[0] = (g == 0) ? (short)qt1[48] : (short)0;
      const bf16x8 bh = *(const bf16x8*)&slb[m0];    // zeros at m>=49
      acc0 = __builtin_amdgcn_mfma_f32_32x32x16_bf16(a0, bh, acc0, 0, 0, 0);
      acc1 = __builtin_amdgcn_mfma_f32_32x32x16_bf16(a1, bh, acc1, 0, 0, 0);
    }

    // epilogue: all 64 rows/tile valid; guard col j < 49; coalesced per r
    const int j = j0 + ln;
    if (j < NN) {
      #pragma unroll
      for (int r = 0; r < 16; ++r) {
        const int i = i0 + (r & 3) + 8 * (r >> 2) + 4 * g;
        const size_t o0 = qbase + (size_t)i * NN + j;
        const size_t o1 = qbase + (size_t)(64 + i) * NN + j;
        Og[o0] = acc0[r] + Vg[o0];
        Og[o1] = acc1[r] + Vg[o1];
      }
    }
  }
}

extern "C" void kernel_launch(void* const* d_in, const int* in_sizes, int n_in,
                              void* d_out, int out_size, void* d_ws, size_t ws_size,
                              hipStream_t stream) {
  (void)in_sizes; (void)n_in; (void)out_size; (void)ws_size;
  const float* v1 = (const float*)d_in[0];
  const float* q1 = (const float*)d_in[1];
  const float* k1 = (const float*)d_in[2];
  float* out = (float*)d_out;

  float*    spart = (float*)d_ws;                     // 1024*2401*4 = 9.83 MB
  unsigned* ctr   = (unsigned*)((char*)d_ws + (size_t)GRID * NN * NN * 4);

  hipMemsetAsync(ctr, 0, 256, stream);                // barrier counter only
  cam_kernel<<<dim3(GRID), dim3(256), 0, stream>>>(k1, v1, q1, spart, ctr, out);
}